// Round 8
// baseline (411.593 us; speedup 1.0000x reference)
//
#include <hip/hip_runtime.h>

#define NB    2048
#define N1    50
#define DIMC  256
#define NHEAD 8

typedef short  s16x8 __attribute__((ext_vector_type(8)));
typedef short  s16x4 __attribute__((ext_vector_type(4)));
typedef float  f32x4 __attribute__((ext_vector_type(4)));
typedef float  f32x2 __attribute__((ext_vector_type(2)));

__device__ __forceinline__ unsigned short f2bf(float f) {
    unsigned int u = __builtin_bit_cast(unsigned int, f);
    u = (u + 0x7FFFu + ((u >> 16) & 1u)) >> 16;
    return (unsigned short)u;
}
__device__ __forceinline__ s16x8 ld8(const unsigned short* p) {
    return *(const s16x8*)p;
}

// ---------------- prep: K-blocked bf16 weights + padded mask (unchanged, proven) ------------
__global__ void prep_kernel(const float* __restrict__ qkv_w, const float* __restrict__ proj_w,
                            const float* __restrict__ mask,
                            unsigned short* __restrict__ wqkvB, unsigned short* __restrict__ wprojB,
                            float* __restrict__ maskP) {
    int idx = blockIdx.x * 256 + threadIdx.x;          // 0 .. 262143
    {
        int wv = idx >> 12, q = (idx >> 6) & 63, k = idx & 63;
        float v = (k < 50) ? ((q < 50) ? mask[(wv * 50 + q) * 50 + k] : 0.f) : -1e30f;
        maskP[idx] = v;
    }
    if (idx < 196608) {
        int ks = idx / 24576, rem = idx - ks * 24576, n = rem >> 5, kk = rem & 31;
        wqkvB[idx] = f2bf(qkv_w[(ks * 32 + kk) * 768 + n]);
    }
    if (idx < 65536) {
        int ks = idx >> 13, rem = idx & 8191, n = rem >> 5, kk = rem & 31;
        wprojB[idx] = f2bf(proj_w[(ks * 32 + kk) * 256 + n]);
    }
}

// ================= K1: QKV GEMM + attention for a 4-HEAD SLICE ==============================
// 4096 blocks (2 per batch), 512 threads = 8 waves, LDS 54,272 B -> 3 blocks/CU (24 waves/CU,
// vs 16 before). Pair mapping keeps both half-blocks of a batch on the same XCD (p, p+8).
// LDS plan: sXC [64][264] (33,792 B) lives ONLY during phase 1 and is aliased by sQ/sK
// afterward (extra barrier after the K-loop). Peak = sQ+sK ([4][64][36] each) + sVT
// ([4][32][68]) = 54,272 B. O goes to global bf16 (og) for the proj kernel.
__global__ __launch_bounds__(512, 6) void qkvattn_kernel(
        const float* __restrict__ x, const float* __restrict__ cls,
        const float* __restrict__ qkv_b, const unsigned short* __restrict__ wqkvB,
        const float* __restrict__ maskP, unsigned short* __restrict__ og) {
    __shared__ __align__(16) char smem_raw[54272];
    unsigned short* S   = (unsigned short*)smem_raw;
    unsigned short* sXC = S;            // [64][264] bf16, phase-1 only (33,792 B)
    unsigned short* sQ  = S;            // [4][64][36] (18,432 B)  -- aliases sXC after b1.5
    unsigned short* sK  = S + 9216;     // [4][64][36] (18,432 B)  -- aliases sXC tail
    unsigned short* sVT = S + 18432;    // [4][32][68] (17,408 B)  -- above sXC, no overlap

    const int p = blockIdx.x, tid = threadIdx.x;
    const int lane = tid & 63, w = tid >> 6;           // w = 0..7
    const int ln15 = lane & 15, quad = lane >> 4, q8 = quad * 8;
    // XCD-preserving pair mapping: blocks p and p+8 (same XCD under round-robin) share batch b.
    const int b  = ((p >> 4) << 3) | (p & 7);          // 0..2047
    const int hh = ((p >> 3) & 1) << 2;                // head offset: 0 or 4
    const int win = b & 63;
    const float SCALE = 0.17677669529663687f;

    // ---- stage xc rows (row0=cls, 1..49=x, 50..63=0), paired u32 LDS writes (R0 pattern)
    #pragma unroll
    for (int i = 0; i < 16; ++i) {
        int pp = i * 512 + tid;
        int r = pp >> 7, c = (pp & 127) * 2;
        float v0, v1;
        if (r == 0)       { v0 = cls[c]; v1 = cls[c + 1]; }
        else if (r <= 49) { const float* px = &x[((size_t)b * 49 + (r - 1)) * 256 + c];
                            f32x2 t = *(const f32x2*)px; v0 = t[0]; v1 = t[1]; }
        else              { v0 = 0.f; v1 = 0.f; }
        *(unsigned int*)&sXC[r * 264 + c] = (unsigned int)f2bf(v0) | ((unsigned int)f2bf(v1) << 16);
    }
    // ---- prefetch phase-1 B frags for ks=0. Wave w owns slice cols w*48..w*48+47 of the
    // 384-col (4-head) QKV slice; global col g = seg*256 + hh*32 + (slice_col & 127).
    s16x8 bcur[3];
    int g0[3];
    #pragma unroll
    for (int nt = 0; nt < 3; ++nt) {
        const int sc0 = w * 48 + nt * 16;
        const int seg = sc0 >> 7;                      // 0=Q 1=K 2=V (wave-uniform per nt)
        g0[nt] = seg * 256 + hh * 32 + (sc0 & 127);
        bcur[nt] = ld8(wqkvB + (g0[nt] + ln15) * 32 + q8);
    }
    __syncthreads();                                    // barrier 1

    // ================= phase 1: [64x256] @ [256x384 slice], barrier-free K-loop ==============
    f32x4 acc[4][3];
    #pragma unroll
    for (int mt = 0; mt < 4; ++mt)
        #pragma unroll
        for (int nt = 0; nt < 3; ++nt) acc[mt][nt] = f32x4{0.f, 0.f, 0.f, 0.f};

    #pragma unroll
    for (int ks = 0; ks < 8; ++ks) {
        s16x8 bnext[3];
        if (ks < 7) {
            const unsigned short* src = wqkvB + (ks + 1) * 24576;
            #pragma unroll
            for (int nt = 0; nt < 3; ++nt)
                bnext[nt] = ld8(src + (g0[nt] + ln15) * 32 + q8);
        }
        s16x8 af[4];
        #pragma unroll
        for (int mt = 0; mt < 4; ++mt)
            af[mt] = ld8(&sXC[(mt * 16 + ln15) * 264 + ks * 32 + q8]);
        #pragma unroll
        for (int mt = 0; mt < 4; ++mt)
            #pragma unroll
            for (int nt = 0; nt < 3; ++nt)
                acc[mt][nt] = __builtin_amdgcn_mfma_f32_16x16x32_bf16(af[mt], bcur[nt], acc[mt][nt], 0, 0, 0);
        if (ks < 7) {
            #pragma unroll
            for (int nt = 0; nt < 3; ++nt) bcur[nt] = bnext[nt];
        }
    }
    __syncthreads();                                    // barrier 1.5: sXC dead -> sQ/sK may alias

    // ---- epilogue: bias (+scale for q), scatter into sQ/sK (stride 36), packed b64 into sVT
    #pragma unroll
    for (int nt = 0; nt < 3; ++nt) {
        const int sc0 = w * 48 + nt * 16;
        const int seg = sc0 >> 7;                      // wave-uniform
        const int gcl = (sc0 & 127) + ln15;            // local col in segment, 0..127
        const int hd = gcl >> 5, dd = gcl & 31;        // local head 0..3, dim 0..31
        const float bias = qkv_b[seg * 256 + hh * 32 + gcl];
        if (seg == 0) {
            #pragma unroll
            for (int mt = 0; mt < 4; ++mt)
                #pragma unroll
                for (int i = 0; i < 4; ++i)
                    sQ[hd * 2304 + (mt * 16 + quad * 4 + i) * 36 + dd] = f2bf((acc[mt][nt][i] + bias) * SCALE);
        } else if (seg == 1) {
            #pragma unroll
            for (int mt = 0; mt < 4; ++mt)
                #pragma unroll
                for (int i = 0; i < 4; ++i)
                    sK[hd * 2304 + (mt * 16 + quad * 4 + i) * 36 + dd] = f2bf(acc[mt][nt][i] + bias);
        } else {
            #pragma unroll
            for (int mt = 0; mt < 4; ++mt) {
                s16x4 pk;
                #pragma unroll
                for (int i = 0; i < 4; ++i) pk[i] = f2bf(acc[mt][nt][i] + bias);
                *(s16x4*)&sVT[(hd * 32 + dd) * 68 + mt * 16 + quad * 4] = pk;
            }
        }
    }
    __syncthreads();                                    // barrier 2

    // ================= phase 2: attention, wave = (local head h, row-half rh) ================
    {
        const int h = w >> 1, rh = w & 1, qt0 = rh * 2;
        // sP aliases this wave's own rh-half of sQ[h]: writes [rh*1152, rh*1152+1143],
        // own bq reads rows rh*32..+31 = [rh*1152, (rh+1)*1152) shorts -- both bq reads happen
        // in the first loop below, BEFORE any P write (R0's two-loop structure).
        unsigned short* sPw = sQ + h * 2304 + rh * 1152;

        s16x8 ak[4];
        #pragma unroll
        for (int kt = 0; kt < 4; ++kt)
            ak[kt] = ld8(&sK[h * 2304 + (kt * 16 + ln15) * 36 + q8]);

        f32x4 st[2][4];
        #pragma unroll
        for (int mt = 0; mt < 2; ++mt) {
            s16x8 bq = ld8(&sQ[h * 2304 + ((qt0 + mt) * 16 + ln15) * 36 + q8]);
            #pragma unroll
            for (int kt = 0; kt < 4; ++kt) {
                f32x4 z = {0.f, 0.f, 0.f, 0.f};
                st[mt][kt] = __builtin_amdgcn_mfma_f32_16x16x32_bf16(ak[kt], bq, z, 0, 0, 0);
            }
        }
        // S^T layout: col(=lane&15)=query, row(=quad*4+reg)=key
        s16x8 pb[2][2];
        #pragma unroll
        for (int mt = 0; mt < 2; ++mt) {
            float sum = 0.f;
            #pragma unroll
            for (int kt = 0; kt < 4; ++kt) {
                f32x4 mk = *(const f32x4*)&maskP[((size_t)(win * 64 + (qt0 + mt) * 16 + ln15)) * 64 + kt * 16 + quad * 4];
                #pragma unroll
                for (int i = 0; i < 4; ++i) {
                    float e = __expf(st[mt][kt][i] + mk[i]);   // no-max softmax; pad keys -> 0
                    st[mt][kt][i] = e;
                    sum += e;
                }
            }
            sum += __shfl_xor(sum, 16, 64);
            sum += __shfl_xor(sum, 32, 64);
            const float inv = 1.f / sum;
            #pragma unroll
            for (int kt = 0; kt < 4; ++kt) {
                s16x4 pk;
                #pragma unroll
                for (int i = 0; i < 4; ++i) pk[i] = f2bf(st[mt][kt][i] * inv);
                *(s16x4*)&sPw[ln15 * 72 + kt * 16 + quad * 4] = pk;   // P[query][key]
            }
            asm volatile("s_waitcnt lgkmcnt(0)" ::: "memory");
            pb[mt][0] = ld8(&sPw[ln15 * 72 + q8]);
            pb[mt][1] = ld8(&sPw[ln15 * 72 + 32 + q8]);
        }
        // O^T = V^T @ P^T : C/D col=query, row=d
        s16x8 av[2][2];
        #pragma unroll
        for (int dt = 0; dt < 2; ++dt)
            #pragma unroll
            for (int kk = 0; kk < 2; ++kk)
                av[dt][kk] = ld8(&sVT[(h * 32 + dt * 16 + ln15) * 68 + kk * 32 + q8]);
        f32x4 o[2][2];
        #pragma unroll
        for (int mt = 0; mt < 2; ++mt)
            #pragma unroll
            for (int dt = 0; dt < 2; ++dt) o[mt][dt] = f32x4{0.f, 0.f, 0.f, 0.f};
        #pragma unroll
        for (int mt = 0; mt < 2; ++mt)
            #pragma unroll
            for (int dt = 0; dt < 2; ++dt)
                #pragma unroll
                for (int kk = 0; kk < 2; ++kk)
                    o[mt][dt] = __builtin_amdgcn_mfma_f32_16x16x32_bf16(av[dt][kk], pb[mt][kk], o[mt][dt], 0, 0, 0);
        // O -> GLOBAL bf16 og[b][tok 64][col 256], cols (hh+h)*32 + ... (all 64 rows, finite)
        #pragma unroll
        for (int mt = 0; mt < 2; ++mt) {
            const int qg = (qt0 + mt) * 16 + ln15;
            #pragma unroll
            for (int dt = 0; dt < 2; ++dt) {
                s16x4 pk;
                #pragma unroll
                for (int i = 0; i < 4; ++i) pk[i] = f2bf(o[mt][dt][i]);
                *(s16x4*)&og[((size_t)b * 64 + qg) * 256 + (hh + h) * 32 + dt * 16 + quad * 4] = pk;
            }
        }
    }
}

// ================= K2: proj GEMM [64x256]@[256x256] per batch ===============================
// 2048 blocks, 512 threads = 8 waves, LDS 33,792 B -> up to 4 blocks/CU. A-tile (O) staged
// bf16->bf16 (no conversion); B direct global->reg (proven pattern); wave = 32 cols x 64 rows.
__global__ __launch_bounds__(512, 6) void proj_kernel(
        const unsigned short* __restrict__ og, const unsigned short* __restrict__ wprojB,
        const float* __restrict__ proj_b, float* __restrict__ out) {
    __shared__ __align__(16) unsigned short sO[64 * 264];

    const int b = blockIdx.x, tid = threadIdx.x;
    const int lane = tid & 63, w = tid >> 6;           // w = 0..7
    const int ln15 = lane & 15, quad = lane >> 4, q8 = quad * 8;

    // stage O tile [64][256] bf16 (direct copy, b128 both sides)
    #pragma unroll
    for (int i = 0; i < 4; ++i) {
        int idx = i * 512 + tid;                       // 0..2047
        int r = idx >> 5, c8 = (idx & 31) * 8;
        s16x8 v = ld8(og + ((size_t)b * 64 + r) * 256 + c8);
        *(s16x8*)&sO[r * 264 + c8] = v;
    }
    // prefetch ks=0 B frags (global, no LDS dep -> overlaps barrier)
    s16x8 b3[2];
    #pragma unroll
    for (int nt = 0; nt < 2; ++nt)
        b3[nt] = ld8(wprojB + (w * 32 + nt * 16 + ln15) * 32 + q8);
    __syncthreads();

    f32x4 a3[4][2];
    #pragma unroll
    for (int mt = 0; mt < 4; ++mt)
        #pragma unroll
        for (int nt = 0; nt < 2; ++nt) a3[mt][nt] = f32x4{0.f, 0.f, 0.f, 0.f};
    #pragma unroll
    for (int ks = 0; ks < 8; ++ks) {
        s16x8 b3n[2];
        if (ks < 7) {
            const unsigned short* src = wprojB + (ks + 1) * 8192;
            #pragma unroll
            for (int nt = 0; nt < 2; ++nt)
                b3n[nt] = ld8(src + (w * 32 + nt * 16 + ln15) * 32 + q8);
        }
        s16x8 af3[4];
        #pragma unroll
        for (int mt = 0; mt < 4; ++mt)
            af3[mt] = ld8(&sO[(mt * 16 + ln15) * 264 + ks * 32 + q8]);
        #pragma unroll
        for (int mt = 0; mt < 4; ++mt)
            #pragma unroll
            for (int nt = 0; nt < 2; ++nt)
                a3[mt][nt] = __builtin_amdgcn_mfma_f32_16x16x32_bf16(af3[mt], b3[nt], a3[mt][nt], 0, 0, 0);
        if (ks < 7) {
            #pragma unroll
            for (int nt = 0; nt < 2; ++nt) b3[nt] = b3n[nt];
        }
    }
    // epilogue: bias + split store (row 0 -> out[:,0], rows 1..49 -> out[:,1:])
    #pragma unroll
    for (int nt = 0; nt < 2; ++nt) {
        const int gc = w * 32 + nt * 16 + ln15;
        const float bias = proj_b[gc];
        #pragma unroll
        for (int mt = 0; mt < 4; ++mt) {
            #pragma unroll
            for (int i = 0; i < 4; ++i) {
                const int t = mt * 16 + quad * 4 + i;
                const float v = a3[mt][nt][i] + bias;
                if (t == 0)      out[(size_t)b * 256 + gc] = v;
                else if (t < 50) out[(size_t)524288 + ((size_t)b * 49 + (t - 1)) * 256 + gc] = v;
            }
        }
    }
}

// ================= FALLBACK: proven R0 fully-fused kernel (used if ws too small) ============
__global__ __launch_bounds__(1024, 4) void fused_kernel(
        const float* __restrict__ x, const float* __restrict__ cls,
        const float* __restrict__ qkv_b, const unsigned short* __restrict__ wqkvB,
        const unsigned short* __restrict__ wprojB, const float* __restrict__ proj_b,
        const float* __restrict__ maskP, float* __restrict__ out) {
    __shared__ __align__(16) char smem_raw[152576];
    unsigned short* S   = (unsigned short*)smem_raw;
    unsigned short* sXC = S;
    unsigned short* sQ  = S + 16896;
    unsigned short* sK  = S + 37376;
    unsigned short* sVT = S + 57856;

    const int b = blockIdx.x, tid = threadIdx.x;
    const int lane = tid & 63, w = tid >> 6;
    const int ln15 = lane & 15, quad = lane >> 4, q8 = quad * 8;
    const int win = b & 63;
    const float SCALE = 0.17677669529663687f;

    #pragma unroll
    for (int i = 0; i < 8; ++i) {
        int p = i * 1024 + tid;
        int r = p >> 7, c = (p & 127) * 2;
        float v0, v1;
        if (r == 0)       { v0 = cls[c]; v1 = cls[c + 1]; }
        else if (r <= 49) { const float* px = &x[((size_t)b * 49 + (r - 1)) * 256 + c];
                            f32x2 t = *(const f32x2*)px; v0 = t[0]; v1 = t[1]; }
        else              { v0 = 0.f; v1 = 0.f; }
        *(unsigned int*)&sXC[r * 264 + c] = (unsigned int)f2bf(v0) | ((unsigned int)f2bf(v1) << 16);
    }
    s16x8 bcur[3];
    #pragma unroll
    for (int nt = 0; nt < 3; ++nt)
        bcur[nt] = ld8(wqkvB + (w * 48 + nt * 16 + ln15) * 32 + q8);
    __syncthreads();

    f32x4 acc[4][3];
    #pragma unroll
    for (int mt = 0; mt < 4; ++mt)
        #pragma unroll
        for (int nt = 0; nt < 3; ++nt) acc[mt][nt] = f32x4{0.f, 0.f, 0.f, 0.f};

    #pragma unroll
    for (int ks = 0; ks < 8; ++ks) {
        s16x8 bnext[3];
        if (ks < 7) {
            const unsigned short* src = wqkvB + (ks + 1) * 24576;
            #pragma unroll
            for (int nt = 0; nt < 3; ++nt)
                bnext[nt] = ld8(src + (w * 48 + nt * 16 + ln15) * 32 + q8);
        }
        s16x8 af[4];
        #pragma unroll
        for (int mt = 0; mt < 4; ++mt)
            af[mt] = ld8(&sXC[(mt * 16 + ln15) * 264 + ks * 32 + q8]);
        #pragma unroll
        for (int mt = 0; mt < 4; ++mt)
            #pragma unroll
            for (int nt = 0; nt < 3; ++nt)
                acc[mt][nt] = __builtin_amdgcn_mfma_f32_16x16x32_bf16(af[mt], bcur[nt], acc[mt][nt], 0, 0, 0);
        if (ks < 7) {
            #pragma unroll
            for (int nt = 0; nt < 3; ++nt) bcur[nt] = bnext[nt];
        }
    }

    #pragma unroll
    for (int nt = 0; nt < 3; ++nt) {
        const int gc = w * 48 + nt * 16 + ln15;
        const int type = (w * 48 + nt * 16) >> 8;
        const int hd = (gc >> 5) & 7, dd = gc & 31;
        const float bias = qkv_b[gc];
        if (type == 0) {
            #pragma unroll
            for (int mt = 0; mt < 4; ++mt)
                #pragma unroll
                for (int i = 0; i < 4; ++i)
                    sQ[hd * 2560 + (mt * 16 + quad * 4 + i) * 40 + dd] = f2bf((acc[mt][nt][i] + bias) * SCALE);
        } else if (type == 1) {
            #pragma unroll
            for (int mt = 0; mt < 4; ++mt)
                #pragma unroll
                for (int i = 0; i < 4; ++i)
                    sK[hd * 2560 + (mt * 16 + quad * 4 + i) * 40 + dd] = f2bf(acc[mt][nt][i] + bias);
        } else {
            #pragma unroll
            for (int mt = 0; mt < 4; ++mt) {
                s16x4 pk;
                #pragma unroll
                for (int i = 0; i < 4; ++i) pk[i] = f2bf(acc[mt][nt][i] + bias);
                *(s16x4*)&sVT[hd * 2304 + dd * 72 + mt * 16 + quad * 4] = pk;
            }
        }
    }
    __syncthreads();

    {
        const int h = w >> 1, rh = w & 1, qt0 = rh * 2;
        unsigned short* sPw = sQ + h * 2560 + rh * 1280;

        s16x8 ak[4];
        #pragma unroll
        for (int kt = 0; kt < 4; ++kt)
            ak[kt] = ld8(&sK[h * 2560 + (kt * 16 + ln15) * 40 + q8]);

        f32x4 st[2][4];
        #pragma unroll
        for (int mt = 0; mt < 2; ++mt) {
            s16x8 bq = ld8(&sQ[h * 2560 + ((qt0 + mt) * 16 + ln15) * 40 + q8]);
            #pragma unroll
            for (int kt = 0; kt < 4; ++kt) {
                f32x4 z = {0.f, 0.f, 0.f, 0.f};
                st[mt][kt] = __builtin_amdgcn_mfma_f32_16x16x32_bf16(ak[kt], bq, z, 0, 0, 0);
            }
        }
        s16x8 pb[2][2];
        #pragma unroll
        for (int mt = 0; mt < 2; ++mt) {
            float sum = 0.f;
            #pragma unroll
            for (int kt = 0; kt < 4; ++kt) {
                f32x4 mk = *(const f32x4*)&maskP[((size_t)(win * 64 + (qt0 + mt) * 16 + ln15)) * 64 + kt * 16 + quad * 4];
                #pragma unroll
                for (int i = 0; i < 4; ++i) {
                    float e = __expf(st[mt][kt][i] + mk[i]);
                    st[mt][kt][i] = e;
                    sum += e;
                }
            }
            sum += __shfl_xor(sum, 16, 64);
            sum += __shfl_xor(sum, 32, 64);
            const float inv = 1.f / sum;
            #pragma unroll
            for (int kt = 0; kt < 4; ++kt) {
                s16x4 pk;
                #pragma unroll
                for (int i = 0; i < 4; ++i) pk[i] = f2bf(st[mt][kt][i] * inv);
                *(s16x4*)&sPw[ln15 * 72 + kt * 16 + quad * 4] = pk;
            }
            asm volatile("s_waitcnt lgkmcnt(0)" ::: "memory");
            pb[mt][0] = ld8(&sPw[ln15 * 72 + q8]);
            pb[mt][1] = ld8(&sPw[ln15 * 72 + 32 + q8]);
        }
        s16x8 av[2][2];
        #pragma unroll
        for (int dt = 0; dt < 2; ++dt)
            #pragma unroll
            for (int kk = 0; kk < 2; ++kk)
                av[dt][kk] = ld8(&sVT[h * 2304 + (dt * 16 + ln15) * 72 + kk * 32 + q8]);
        f32x4 o[2][2];
        #pragma unroll
        for (int mt = 0; mt < 2; ++mt)
            #pragma unroll
            for (int dt = 0; dt < 2; ++dt) o[mt][dt] = f32x4{0.f, 0.f, 0.f, 0.f};
        #pragma unroll
        for (int mt = 0; mt < 2; ++mt)
            #pragma unroll
            for (int dt = 0; dt < 2; ++dt)
                #pragma unroll
                for (int kk = 0; kk < 2; ++kk)
                    o[mt][dt] = __builtin_amdgcn_mfma_f32_16x16x32_bf16(av[dt][kk], pb[mt][kk], o[mt][dt], 0, 0, 0);
        #pragma unroll
        for (int mt = 0; mt < 2; ++mt) {
            const int qg = (qt0 + mt) * 16 + ln15;
            #pragma unroll
            for (int dt = 0; dt < 2; ++dt) {
                s16x4 pk;
                #pragma unroll
                for (int i = 0; i < 4; ++i) pk[i] = f2bf(o[mt][dt][i]);
                *(s16x4*)&sXC[qg * 264 + h * 32 + dt * 16 + quad * 4] = pk;
            }
        }
    }
    __syncthreads();

    {
        const int wm3 = w >> 3, wn3 = w & 7;
        s16x8 b3[2];
        #pragma unroll
        for (int nt = 0; nt < 2; ++nt)
            b3[nt] = ld8(wprojB + (wn3 * 32 + nt * 16 + ln15) * 32 + q8);
        f32x4 a3[2][2];
        #pragma unroll
        for (int mt = 0; mt < 2; ++mt)
            #pragma unroll
            for (int nt = 0; nt < 2; ++nt) a3[mt][nt] = f32x4{0.f, 0.f, 0.f, 0.f};
        #pragma unroll
        for (int ks = 0; ks < 8; ++ks) {
            s16x8 b3n[2];
            if (ks < 7) {
                const unsigned short* src = wprojB + (ks + 1) * 8192;
                #pragma unroll
                for (int nt = 0; nt < 2; ++nt)
                    b3n[nt] = ld8(src + (wn3 * 32 + nt * 16 + ln15) * 32 + q8);
            }
            s16x8 af3[2];
            #pragma unroll
            for (int mt = 0; mt < 2; ++mt)
                af3[mt] = ld8(&sXC[(wm3 * 32 + mt * 16 + ln15) * 264 + ks * 32 + q8]);
            #pragma unroll
            for (int mt = 0; mt < 2; ++mt)
                #pragma unroll
                for (int nt = 0; nt < 2; ++nt)
                    a3[mt][nt] = __builtin_amdgcn_mfma_f32_16x16x32_bf16(af3[mt], b3[nt], a3[mt][nt], 0, 0, 0);
            if (ks < 7) {
                #pragma unroll
                for (int nt = 0; nt < 2; ++nt) b3[nt] = b3n[nt];
            }
        }
        #pragma unroll
        for (int nt = 0; nt < 2; ++nt) {
            const int gc = wn3 * 32 + nt * 16 + ln15;
            const float bias = proj_b[gc];
            #pragma unroll
            for (int mt = 0; mt < 2; ++mt) {
                #pragma unroll
                for (int i = 0; i < 4; ++i) {
                    const int t = wm3 * 32 + mt * 16 + quad * 4 + i;
                    const float v = a3[mt][nt][i] + bias;
                    if (t == 0)      out[(size_t)b * 256 + gc] = v;
                    else if (t < 50) out[(size_t)524288 + ((size_t)b * 49 + (t - 1)) * 256 + gc] = v;
                }
            }
        }
    }
}

extern "C" void kernel_launch(void* const* d_in, const int* in_sizes, int n_in,
                              void* d_out, int out_size, void* d_ws, size_t ws_size,
                              hipStream_t stream) {
    const float* x      = (const float*)d_in[0];
    const float* mask   = (const float*)d_in[1];
    const float* cls    = (const float*)d_in[2];
    const float* qkv_w  = (const float*)d_in[3];
    const float* qkv_b  = (const float*)d_in[4];
    const float* proj_w = (const float*)d_in[5];
    const float* proj_b = (const float*)d_in[6];
    float* out = (float*)d_out;

    // workspace layout: weights+mask (1.57 MB) + O buffer (67.1 MB)
    unsigned short* wqkvB  = (unsigned short*)d_ws;                        // 393,216 B
    unsigned short* wprojB = (unsigned short*)((char*)d_ws + 393216);      // 131,072 B
    float*          maskP  = (float*)((char*)d_ws + 524288);               // 1,048,576 B
    unsigned short* og     = (unsigned short*)((char*)d_ws + 1572864);     // 67,108,864 B

    prep_kernel<<<1024, 256, 0, stream>>>(qkv_w, proj_w, mask, wqkvB, wprojB, maskP);
    if (ws_size >= (size_t)1572864 + 67108864) {
        qkvattn_kernel<<<4096, 512, 0, stream>>>(x, cls, qkv_b, wqkvB, maskP, og);
        proj_kernel<<<2048, 512, 0, stream>>>(og, wprojB, proj_b, out);
    } else {
        fused_kernel<<<NB, 1024, 0, stream>>>(x, cls, qkv_b, wqkvB, wprojB, proj_b, maskP, out);
    }
}